// Round 1
// baseline (3394.455 us; speedup 1.0000x reference)
//
#include <hip/hip_runtime.h>
#include <stdint.h>

typedef __bf16 bf16;
typedef __attribute__((ext_vector_type(8))) __bf16 bf16x8;
typedef __attribute__((ext_vector_type(4))) float f32x4;

#define GRU_H 2048
#define ODIM 96
#define PADX 128
#define BATCH 1024
#define TSTEPS 25

__device__ __forceinline__ float sigm(float x) { return 1.f / (1.f + __expf(-x)); }

// ---------------- init / convert kernels ----------------
__global__ void k_cvt(const float* __restrict__ s, bf16* __restrict__ d, int n) {
  int stride = gridDim.x * blockDim.x;
  for (int i = blockIdx.x * blockDim.x + threadIdx.x; i < n; i += stride)
    d[i] = (bf16)s[i];
}

__global__ void k_cvt_pad(const float* __restrict__ s, bf16* __restrict__ d,
                          int rows, int cin, int cout) {
  int n = rows * cout;
  int stride = gridDim.x * blockDim.x;
  for (int i = blockIdx.x * blockDim.x + threadIdx.x; i < n; i += stride) {
    int r = i / cout, c = i - r * cout;
    d[i] = (c < cin) ? (bf16)s[r * cin + c] : (bf16)0.f;
  }
}

__global__ void k_init_h(const float* __restrict__ s, float* __restrict__ hf,
                         bf16* __restrict__ hb, int n) {
  int stride = gridDim.x * blockDim.x;
  for (int i = blockIdx.x * blockDim.x + threadIdx.x; i < n; i += stride) {
    float v = s[i];
    hf[i] = v;
    hb[i] = (bf16)v;
  }
}

// ---------------- fused GRU layer kernel ----------------
// Block: 512 threads = 8 waves (4 m-waves x 2 n-waves). Tile: 128 rows x 64 H-cols.
// grid.x = H/64 = 32 (H tile), grid.y = BATCH/128 = 8 (M tile).
// Computes h_new = GRUCell(x, h_prev) for a tile, fp32 accumulate via bf16 MFMA.
__global__ __launch_bounds__(512, 1) void k_gru(
    const bf16* __restrict__ xb, int kx,          // x input [1024][kx], kx = 128 or 2048
    const bf16* __restrict__ hb,                  // h_prev bf16 [1024][2048]
    const bf16* __restrict__ wih,                 // [3*2048][kx]
    const bf16* __restrict__ whh,                 // [3*2048][2048]
    const float* __restrict__ bih, const float* __restrict__ bhh,
    const float* __restrict__ hprevf,             // h_prev fp32 master
    float* __restrict__ hnewf, bf16* __restrict__ hnewb) {
  __shared__ alignas(16) char sA[128 * 128];      // 128 rows x 64 bf16 (swizzled)
  __shared__ alignas(16) char sB[192 * 128];      // 3 gates x 64 rows x 64 bf16

  const int tid = threadIdx.x;
  const int l = tid & 63;
  const int w = tid >> 6;
  const int wm = w >> 1, wn = w & 1;
  const int bn0 = blockIdx.x * 64;
  const int bm0 = blockIdx.y * 128;
  const int lm = l >> 4, ln = l & 15;

  f32x4 accR[2][2] = {};
  f32x4 accZ[2][2] = {};
  f32x4 accNH[2][2] = {};
  f32x4 accNI[2][2] = {};

  auto phase = [&](const bf16* __restrict__ A, const bf16* __restrict__ W, int K,
                   f32x4 (&accN)[2][2]) {
    for (int k0 = 0; k0 < K; k0 += 64) {
      __syncthreads();
      // stage A: 128 rows x 64 cols = 1024 x 16B chunks; swizzle slot ^= row&7
      {
        int c = tid;
#pragma unroll
        for (int it = 0; it < 2; ++it, c += 512) {
          int row = c >> 3, slot = c & 7;
          const bf16* src = A + (size_t)(bm0 + row) * K + k0 + slot * 8;
          *(int4*)&sA[row * 128 + ((slot ^ (row & 7)) << 4)] = *(const int4*)src;
        }
      }
      // stage B: 3 gates x 64 rows x 64 cols = 1536 x 16B chunks
      {
        int c = tid;
#pragma unroll
        for (int it = 0; it < 3; ++it, c += 512) {
          int row = c >> 3, slot = c & 7;
          int g = row >> 6, r = row & 63;
          const bf16* src = W + (size_t)(g * GRU_H + bn0 + r) * K + k0 + slot * 8;
          *(int4*)&sB[row * 128 + ((slot ^ (row & 7)) << 4)] = *(const int4*)src;
        }
      }
      __syncthreads();
#pragma unroll
      for (int kf = 0; kf < 2; ++kf) {
        bf16x8 af[2];
#pragma unroll
        for (int mf = 0; mf < 2; ++mf) {
          int row = wm * 32 + mf * 16 + ln;
          int slot = kf * 4 + lm;
          af[mf] = *(const bf16x8*)&sA[row * 128 + ((slot ^ (row & 7)) << 4)];
        }
        bf16x8 bfr[3][2];
#pragma unroll
        for (int g = 0; g < 3; ++g)
#pragma unroll
          for (int nf = 0; nf < 2; ++nf) {
            int row = g * 64 + wn * 32 + nf * 16 + ln;
            int slot = kf * 4 + lm;
            bfr[g][nf] = *(const bf16x8*)&sB[row * 128 + ((slot ^ (row & 7)) << 4)];
          }
#pragma unroll
        for (int mf = 0; mf < 2; ++mf)
#pragma unroll
          for (int nf = 0; nf < 2; ++nf) {
            accR[mf][nf] = __builtin_amdgcn_mfma_f32_16x16x32_bf16(af[mf], bfr[0][nf], accR[mf][nf], 0, 0, 0);
            accZ[mf][nf] = __builtin_amdgcn_mfma_f32_16x16x32_bf16(af[mf], bfr[1][nf], accZ[mf][nf], 0, 0, 0);
            accN[mf][nf] = __builtin_amdgcn_mfma_f32_16x16x32_bf16(af[mf], bfr[2][nf], accN[mf][nf], 0, 0, 0);
          }
      }
    }
  };

  phase(hb, whh, GRU_H, accNH);   // gh contributions (r,z accumulate; n_h separate)
  phase(xb, wih, kx, accNI);      // gi contributions (r,z accumulate; n_i separate)

  // ---- GRU epilogue ----
#pragma unroll
  for (int nf = 0; nf < 2; ++nf) {
    int j = bn0 + wn * 32 + nf * 16 + ln;
    float br = bih[j] + bhh[j];
    float bz = bih[GRU_H + j] + bhh[GRU_H + j];
    float bin = bih[2 * GRU_H + j];
    float bhn = bhh[2 * GRU_H + j];
#pragma unroll
    for (int mf = 0; mf < 2; ++mf) {
#pragma unroll
      for (int rr = 0; rr < 4; ++rr) {
        int m = bm0 + wm * 32 + mf * 16 + lm * 4 + rr;
        size_t idx = (size_t)m * GRU_H + j;
        float hp = hprevf[idx];
        float rg = sigm(accR[mf][nf][rr] + br);
        float zg = sigm(accZ[mf][nf][rr] + bz);
        float ng = tanhf(accNI[mf][nf][rr] + bin + rg * (accNH[mf][nf][rr] + bhn));
        float hn = (1.f - zg) * ng + zg * hp;
        hnewf[idx] = hn;
        hnewb[idx] = (bf16)hn;
      }
    }
  }
}

// ---------------- FC (split-K) ----------------
// grid.x = 16 K-chunks of 128, grid.y = 16 M-tiles of 64. 256 thr = 4 waves.
__global__ __launch_bounds__(256, 1) void k_fc_part(const bf16* __restrict__ h1b,
                                                    const bf16* __restrict__ wfc,
                                                    float* __restrict__ part) {
  const int kc = blockIdx.x;
  const int mt = blockIdx.y;
  const int l = threadIdx.x & 63, w = threadIdx.x >> 6;
  const int lm = l >> 4, ln = l & 15;
  const int m0 = mt * 64 + w * 16;
  const int k0 = kc * 128;
  f32x4 acc[6] = {};
#pragma unroll
  for (int kf = 0; kf < 4; ++kf) {
    bf16x8 a = *(const bf16x8*)&h1b[(size_t)(m0 + ln) * GRU_H + k0 + kf * 32 + lm * 8];
#pragma unroll
    for (int nf = 0; nf < 6; ++nf) {
      bf16x8 b = *(const bf16x8*)&wfc[(size_t)(nf * 16 + ln) * GRU_H + k0 + kf * 32 + lm * 8];
      acc[nf] = __builtin_amdgcn_mfma_f32_16x16x32_bf16(a, b, acc[nf], 0, 0, 0);
    }
  }
  float* base = part + (size_t)kc * (BATCH * ODIM);
#pragma unroll
  for (int nf = 0; nf < 6; ++nf)
#pragma unroll
    for (int rr = 0; rr < 4; ++rr)
      base[(size_t)(m0 + lm * 4 + rr) * ODIM + nf * 16 + ln] = acc[nf][rr];
}

__global__ void k_fc_red(const float* __restrict__ part, const float* __restrict__ bfc,
                         float* __restrict__ dout, bf16* __restrict__ decb, int t) {
  int i = blockIdx.x * blockDim.x + threadIdx.x;
  if (i >= BATCH * ODIM) return;
  int m = i / ODIM, n = i - m * ODIM;
  float s = bfc[n];
#pragma unroll
  for (int kc = 0; kc < 16; ++kc) s += part[(size_t)kc * (BATCH * ODIM) + i];
  s = sigm(s);
  dout[(size_t)m * (TSTEPS * ODIM) + t * ODIM + n] = s;
  decb[m * PADX + n] = (bf16)s;
}

// ---------------- launch ----------------
extern "C" void kernel_launch(void* const* d_in, const int* in_sizes, int n_in,
                              void* d_out, int out_size, void* d_ws, size_t ws_size,
                              hipStream_t stream) {
  const float* input   = (const float*)d_in[0];
  const float* hiddens = (const float*)d_in[2];
  const float* W_ih0   = (const float*)d_in[3];
  const float* W_hh0   = (const float*)d_in[4];
  const float* b_ih0   = (const float*)d_in[5];
  const float* b_hh0   = (const float*)d_in[6];
  const float* W_ih1   = (const float*)d_in[7];
  const float* W_hh1   = (const float*)d_in[8];
  const float* b_ih1   = (const float*)d_in[9];
  const float* b_hh1   = (const float*)d_in[10];
  const float* W_fc    = (const float*)d_in[11];
  const float* b_fc    = (const float*)d_in[12];
  float* out = (float*)d_out;

  char* p = (char*)d_ws;
  auto take = [&](size_t n) { char* q = p; p += (n + 255) & ~(size_t)255; return q; };
  bf16* wih0b = (bf16*)take((size_t)3 * GRU_H * PADX * 2);
  bf16* whh0b = (bf16*)take((size_t)3 * GRU_H * GRU_H * 2);
  bf16* wih1b = (bf16*)take((size_t)3 * GRU_H * GRU_H * 2);
  bf16* whh1b = (bf16*)take((size_t)3 * GRU_H * GRU_H * 2);
  bf16* wfcb  = (bf16*)take((size_t)ODIM * GRU_H * 2);
  bf16* decb  = (bf16*)take((size_t)BATCH * PADX * 2);
  float* h0f[2], *h1f[2];
  bf16* h0b[2], *h1b[2];
  h0f[0] = (float*)take((size_t)BATCH * GRU_H * 4);
  h0f[1] = (float*)take((size_t)BATCH * GRU_H * 4);
  h1f[0] = (float*)take((size_t)BATCH * GRU_H * 4);
  h1f[1] = (float*)take((size_t)BATCH * GRU_H * 4);
  h0b[0] = (bf16*)take((size_t)BATCH * GRU_H * 2);
  h0b[1] = (bf16*)take((size_t)BATCH * GRU_H * 2);
  h1b[0] = (bf16*)take((size_t)BATCH * GRU_H * 2);
  h1b[1] = (bf16*)take((size_t)BATCH * GRU_H * 2);
  float* fcpart = (float*)take((size_t)16 * BATCH * ODIM * 4);

  // one-time (per launch) conversions
  k_cvt_pad<<<768, 256, 0, stream>>>(W_ih0, wih0b, 3 * GRU_H, ODIM, PADX);
  k_cvt<<<2048, 256, 0, stream>>>(W_hh0, whh0b, 3 * GRU_H * GRU_H);
  k_cvt<<<2048, 256, 0, stream>>>(W_ih1, wih1b, 3 * GRU_H * GRU_H);
  k_cvt<<<2048, 256, 0, stream>>>(W_hh1, whh1b, 3 * GRU_H * GRU_H);
  k_cvt<<<192, 256, 0, stream>>>(W_fc, wfcb, ODIM * GRU_H);
  k_cvt_pad<<<512, 256, 0, stream>>>(input, decb, BATCH, ODIM, PADX);
  k_init_h<<<2048, 256, 0, stream>>>(hiddens, h0f[0], h0b[0], BATCH * GRU_H);
  k_init_h<<<2048, 256, 0, stream>>>(hiddens + (size_t)BATCH * GRU_H, h1f[0], h1b[0], BATCH * GRU_H);

  int cur = 0;
  for (int t = 0; t < TSTEPS; ++t) {
    int nxt = cur ^ 1;
    k_gru<<<dim3(32, 8), 512, 0, stream>>>(decb, PADX, h0b[cur], wih0b, whh0b,
                                           b_ih0, b_hh0, h0f[cur], h0f[nxt], h0b[nxt]);
    k_gru<<<dim3(32, 8), 512, 0, stream>>>(h0b[nxt], GRU_H, h1b[cur], wih1b, whh1b,
                                           b_ih1, b_hh1, h1f[cur], h1f[nxt], h1b[nxt]);
    k_fc_part<<<dim3(16, 16), 256, 0, stream>>>(h1b[nxt], wfcb, fcpart);
    k_fc_red<<<384, 256, 0, stream>>>(fcpart, b_fc, out, decb, t);
    cur = nxt;
  }
}

// Round 2
// 2829.776 us; speedup vs baseline: 1.1995x; 1.1995x over previous
//
#include <hip/hip_runtime.h>
#include <stdint.h>

typedef __bf16 bf16;
typedef __attribute__((ext_vector_type(8))) __bf16 bf16x8;
typedef __attribute__((ext_vector_type(4))) float f32x4;

#define GRU_H 2048
#define ODIM 96
#define PADX 128
#define BATCH 1024
#define TSTEPS 25

__device__ __forceinline__ float sigm(float x) { return 1.f / (1.f + __expf(-x)); }

__device__ __forceinline__ void gload16(const void* g, void* l) {
  __builtin_amdgcn_global_load_lds((const __attribute__((address_space(1))) uint32_t*)g,
                                   (__attribute__((address_space(3))) uint32_t*)l, 16, 0, 0);
}

// ---------------- init / convert kernels ----------------
__global__ void k_cvt(const float* __restrict__ s, bf16* __restrict__ d, int n) {
  int stride = gridDim.x * blockDim.x;
  for (int i = blockIdx.x * blockDim.x + threadIdx.x; i < n; i += stride)
    d[i] = (bf16)s[i];
}

__global__ void k_cvt_pad(const float* __restrict__ s, bf16* __restrict__ d,
                          int rows, int cin, int cout) {
  int n = rows * cout;
  int stride = gridDim.x * blockDim.x;
  for (int i = blockIdx.x * blockDim.x + threadIdx.x; i < n; i += stride) {
    int r = i / cout, c = i - r * cout;
    d[i] = (c < cin) ? (bf16)s[r * cin + c] : (bf16)0.f;
  }
}

__global__ void k_init_h(const float* __restrict__ s, float* __restrict__ hf,
                         bf16* __restrict__ hb, int n) {
  int stride = gridDim.x * blockDim.x;
  for (int i = blockIdx.x * blockDim.x + threadIdx.x; i < n; i += stride) {
    float v = s[i];
    hf[i] = v;
    hb[i] = (bf16)v;
  }
}

// ---------------- fused GRU layer kernel ----------------
// Block: 512 threads = 8 waves (4 m-waves x 2 n-waves). Tile: 128 rows x 64 H-cols x 3 gates.
// grid.x = H/64 = 32, grid.y = BATCH/128 = 8  ->  256 blocks = 1 block/CU.
// Depth-2 prefetch via global_load_lds into 3 LDS buffers, counted vmcnt (never 0 mid-loop).
// LDS layout per buffer: A[128 rows][8 slots of 16B] then B[192 rows][8 slots], slot XOR-swizzled
// by row&7 (swizzle applied on the GLOBAL source address; LDS write is linear per rule #21).
__global__ __launch_bounds__(512, 1) void k_gru(
    const bf16* __restrict__ xb, int kx,          // x input [1024][kx], kx = 128 or 2048
    const bf16* __restrict__ hb,                  // h_prev bf16 [1024][2048]
    const bf16* __restrict__ wih,                 // [3*2048][kx]
    const bf16* __restrict__ whh,                 // [3*2048][2048]
    const float* __restrict__ bih, const float* __restrict__ bhh,
    const float* __restrict__ hprevf,             // h_prev fp32 master
    float* __restrict__ hnewf, bf16* __restrict__ hnewb) {
  __shared__ alignas(16) char sm[3][40960];       // 3 x (16KB A + 24KB B) = 120 KB

  const int tid = threadIdx.x;
  const int l = tid & 63;
  const int w = tid >> 6;
  const int wm = w >> 1, wn = w & 1;
  const int bn0 = blockIdx.x * 64;
  const int bm0 = blockIdx.y * 128;
  const int lm = l >> 4, ln = l & 15;

  const int S1 = GRU_H / 64;      // 32 steps of the hh phase
  const int S2 = kx / 64;         // 2 or 32 steps of the ih phase
  const int S = S1 + S2;

  f32x4 accR[2][2] = {};
  f32x4 accZ[2][2] = {};
  f32x4 accNH[2][2] = {};
  f32x4 accNI[2][2] = {};

  // stage one 64-wide K-slice of A(128 rows) + B(3x64 rows) into sm[buf]
  auto stageStep = [&](int buf, int step) {
    const bf16* A; const bf16* W; int K; int k0;
    if (step < S1) { A = hb; W = whh; K = GRU_H; k0 = step * 64; }
    else           { A = xb; W = wih; K = kx;    k0 = (step - S1) * 64; }
    char* sb = &sm[buf][0];
#pragma unroll
    for (int it = 0; it < 2; ++it) {              // A: 1024 chunks of 16B
      int c = it * 512 + tid;
      int row = c >> 3, pos = c & 7, slot = pos ^ (row & 7);
      const bf16* src = A + (size_t)(bm0 + row) * K + k0 + slot * 8;
      char* dst = sb + ((it * 512 + (tid & ~63)) << 4);   // wave-uniform base + lane*16
      gload16(src, dst);
    }
#pragma unroll
    for (int it = 0; it < 3; ++it) {              // B: 1536 chunks of 16B
      int c = it * 512 + tid;
      int row = c >> 3, pos = c & 7, slot = pos ^ (row & 7);
      int g = row >> 6, r = row & 63;
      const bf16* src = W + (size_t)(g * GRU_H + bn0 + r) * K + k0 + slot * 8;
      char* dst = sb + 16384 + ((it * 512 + (tid & ~63)) << 4);
      gload16(src, dst);
    }
  };

  auto computeStep = [&](int buf, f32x4 (&accN)[2][2]) {
    const char* bp = &sm[buf][0];
#pragma unroll
    for (int kf = 0; kf < 2; ++kf) {
      bf16x8 af[2];
#pragma unroll
      for (int mf = 0; mf < 2; ++mf) {
        int row = wm * 32 + mf * 16 + ln;
        int pos = (kf * 4 + lm) ^ (row & 7);
        af[mf] = *(const bf16x8*)(bp + row * 128 + (pos << 4));
      }
      bf16x8 bq[3][2];
#pragma unroll
      for (int g = 0; g < 3; ++g)
#pragma unroll
        for (int nf = 0; nf < 2; ++nf) {
          int row = g * 64 + wn * 32 + nf * 16 + ln;
          int pos = (kf * 4 + lm) ^ (row & 7);
          bq[g][nf] = *(const bf16x8*)(bp + 16384 + row * 128 + (pos << 4));
        }
#pragma unroll
      for (int mf = 0; mf < 2; ++mf)
#pragma unroll
        for (int nf = 0; nf < 2; ++nf) {
          accR[mf][nf] = __builtin_amdgcn_mfma_f32_16x16x32_bf16(af[mf], bq[0][nf], accR[mf][nf], 0, 0, 0);
          accZ[mf][nf] = __builtin_amdgcn_mfma_f32_16x16x32_bf16(af[mf], bq[1][nf], accZ[mf][nf], 0, 0, 0);
          accN[mf][nf] = __builtin_amdgcn_mfma_f32_16x16x32_bf16(af[mf], bq[2][nf], accN[mf][nf], 0, 0, 0);
        }
    }
  };

  // prologue: fill pipeline 2 deep
  stageStep(0, 0);
  stageStep(1, 1);

  int bc = 0;                                     // buffer holding step s
  for (int s = 0; s < S; ++s) {
    if (s + 2 < S) {
      int b2 = bc + 2; if (b2 >= 3) b2 -= 3;
      stageStep(b2, s + 2);
      // 2 newer stages (10 loads) may stay in flight; stage(s) must be drained.
      asm volatile("s_waitcnt vmcnt(10)" ::: "memory");
    } else if (s + 1 < S) {
      asm volatile("s_waitcnt vmcnt(5)" ::: "memory");
    } else {
      asm volatile("s_waitcnt vmcnt(0)" ::: "memory");
    }
    __builtin_amdgcn_s_barrier();                 // sm[bc] now fully written, all waves
    if (s < S1) computeStep(bc, accNH);
    else        computeStep(bc, accNI);
    // drain this wave's ds_reads, then barrier: no wave may overwrite sm[bc]
    // (next iter stages into (s+3)%3 == bc) while another still reads it.
    asm volatile("s_waitcnt lgkmcnt(0)" ::: "memory");
    __builtin_amdgcn_s_barrier();
    ++bc; if (bc == 3) bc = 0;
  }

  // ---- GRU epilogue ----
#pragma unroll
  for (int nf = 0; nf < 2; ++nf) {
    int j = bn0 + wn * 32 + nf * 16 + ln;
    float br = bih[j] + bhh[j];
    float bz = bih[GRU_H + j] + bhh[GRU_H + j];
    float bin = bih[2 * GRU_H + j];
    float bhn = bhh[2 * GRU_H + j];
#pragma unroll
    for (int mf = 0; mf < 2; ++mf) {
#pragma unroll
      for (int rr = 0; rr < 4; ++rr) {
        int m = bm0 + wm * 32 + mf * 16 + lm * 4 + rr;
        size_t idx = (size_t)m * GRU_H + j;
        float hp = hprevf[idx];
        float rg = sigm(accR[mf][nf][rr] + br);
        float zg = sigm(accZ[mf][nf][rr] + bz);
        float ng = tanhf(accNI[mf][nf][rr] + bin + rg * (accNH[mf][nf][rr] + bhn));
        float hn = (1.f - zg) * ng + zg * hp;
        hnewf[idx] = hn;
        hnewb[idx] = (bf16)hn;
      }
    }
  }
}

// ---------------- FC (split-K) ----------------
// grid.x = 16 K-chunks of 128, grid.y = 16 M-tiles of 64. 256 thr = 4 waves.
__global__ __launch_bounds__(256, 1) void k_fc_part(const bf16* __restrict__ h1b,
                                                    const bf16* __restrict__ wfc,
                                                    float* __restrict__ part) {
  const int kc = blockIdx.x;
  const int mt = blockIdx.y;
  const int l = threadIdx.x & 63, w = threadIdx.x >> 6;
  const int lm = l >> 4, ln = l & 15;
  const int m0 = mt * 64 + w * 16;
  const int k0 = kc * 128;
  f32x4 acc[6] = {};
#pragma unroll
  for (int kf = 0; kf < 4; ++kf) {
    bf16x8 a = *(const bf16x8*)&h1b[(size_t)(m0 + ln) * GRU_H + k0 + kf * 32 + lm * 8];
#pragma unroll
    for (int nf = 0; nf < 6; ++nf) {
      bf16x8 b = *(const bf16x8*)&wfc[(size_t)(nf * 16 + ln) * GRU_H + k0 + kf * 32 + lm * 8];
      acc[nf] = __builtin_amdgcn_mfma_f32_16x16x32_bf16(a, b, acc[nf], 0, 0, 0);
    }
  }
  float* base = part + (size_t)kc * (BATCH * ODIM);
#pragma unroll
  for (int nf = 0; nf < 6; ++nf)
#pragma unroll
    for (int rr = 0; rr < 4; ++rr)
      base[(size_t)(m0 + lm * 4 + rr) * ODIM + nf * 16 + ln] = acc[nf][rr];
}

__global__ void k_fc_red(const float* __restrict__ part, const float* __restrict__ bfc,
                         float* __restrict__ dout, bf16* __restrict__ decb, int t) {
  int i = blockIdx.x * blockDim.x + threadIdx.x;
  if (i >= BATCH * ODIM) return;
  int m = i / ODIM, n = i - m * ODIM;
  float s = bfc[n];
#pragma unroll
  for (int kc = 0; kc < 16; ++kc) s += part[(size_t)kc * (BATCH * ODIM) + i];
  s = sigm(s);
  dout[(size_t)m * (TSTEPS * ODIM) + t * ODIM + n] = s;
  decb[m * PADX + n] = (bf16)s;
}

// ---------------- launch ----------------
extern "C" void kernel_launch(void* const* d_in, const int* in_sizes, int n_in,
                              void* d_out, int out_size, void* d_ws, size_t ws_size,
                              hipStream_t stream) {
  const float* input   = (const float*)d_in[0];
  const float* hiddens = (const float*)d_in[2];
  const float* W_ih0   = (const float*)d_in[3];
  const float* W_hh0   = (const float*)d_in[4];
  const float* b_ih0   = (const float*)d_in[5];
  const float* b_hh0   = (const float*)d_in[6];
  const float* W_ih1   = (const float*)d_in[7];
  const float* W_hh1   = (const float*)d_in[8];
  const float* b_ih1   = (const float*)d_in[9];
  const float* b_hh1   = (const float*)d_in[10];
  const float* W_fc    = (const float*)d_in[11];
  const float* b_fc    = (const float*)d_in[12];
  float* out = (float*)d_out;

  char* p = (char*)d_ws;
  auto take = [&](size_t n) { char* q = p; p += (n + 255) & ~(size_t)255; return q; };
  bf16* wih0b = (bf16*)take((size_t)3 * GRU_H * PADX * 2);
  bf16* whh0b = (bf16*)take((size_t)3 * GRU_H * GRU_H * 2);
  bf16* wih1b = (bf16*)take((size_t)3 * GRU_H * GRU_H * 2);
  bf16* whh1b = (bf16*)take((size_t)3 * GRU_H * GRU_H * 2);
  bf16* wfcb  = (bf16*)take((size_t)ODIM * GRU_H * 2);
  bf16* decb  = (bf16*)take((size_t)BATCH * PADX * 2);
  float* h0f[2], *h1f[2];
  bf16* h0b[2], *h1b[2];
  h0f[0] = (float*)take((size_t)BATCH * GRU_H * 4);
  h0f[1] = (float*)take((size_t)BATCH * GRU_H * 4);
  h1f[0] = (float*)take((size_t)BATCH * GRU_H * 4);
  h1f[1] = (float*)take((size_t)BATCH * GRU_H * 4);
  h0b[0] = (bf16*)take((size_t)BATCH * GRU_H * 2);
  h0b[1] = (bf16*)take((size_t)BATCH * GRU_H * 2);
  h1b[0] = (bf16*)take((size_t)BATCH * GRU_H * 2);
  h1b[1] = (bf16*)take((size_t)BATCH * GRU_H * 2);
  float* fcpart = (float*)take((size_t)16 * BATCH * ODIM * 4);

  // one-time (per launch) conversions
  k_cvt_pad<<<768, 256, 0, stream>>>(W_ih0, wih0b, 3 * GRU_H, ODIM, PADX);
  k_cvt<<<2048, 256, 0, stream>>>(W_hh0, whh0b, 3 * GRU_H * GRU_H);
  k_cvt<<<2048, 256, 0, stream>>>(W_ih1, wih1b, 3 * GRU_H * GRU_H);
  k_cvt<<<2048, 256, 0, stream>>>(W_hh1, whh1b, 3 * GRU_H * GRU_H);
  k_cvt<<<192, 256, 0, stream>>>(W_fc, wfcb, ODIM * GRU_H);
  k_cvt_pad<<<512, 256, 0, stream>>>(input, decb, BATCH, ODIM, PADX);
  k_init_h<<<2048, 256, 0, stream>>>(hiddens, h0f[0], h0b[0], BATCH * GRU_H);
  k_init_h<<<2048, 256, 0, stream>>>(hiddens + (size_t)BATCH * GRU_H, h1f[0], h1b[0], BATCH * GRU_H);

  int cur = 0;
  for (int t = 0; t < TSTEPS; ++t) {
    int nxt = cur ^ 1;
    k_gru<<<dim3(32, 8), 512, 0, stream>>>(decb, PADX, h0b[cur], wih0b, whh0b,
                                           b_ih0, b_hh0, h0f[cur], h0f[nxt], h0b[nxt]);
    k_gru<<<dim3(32, 8), 512, 0, stream>>>(h0b[nxt], GRU_H, h1b[cur], wih1b, whh1b,
                                           b_ih1, b_hh1, h1f[cur], h1f[nxt], h1b[nxt]);
    k_fc_part<<<dim3(16, 16), 256, 0, stream>>>(h1b[nxt], wfcb, fcpart);
    k_fc_red<<<384, 256, 0, stream>>>(fcpart, b_fc, out, decb, t);
    cur = nxt;
  }
}